// Round 6
// baseline (767.102 us; speedup 1.0000x reference)
//
#include <hip/hip_runtime.h>
#include <math.h>

#define NWAY 5
#define NSUP 25
#define NZV  125
#define DF   640
#define NQ   75
#define TPB  640   // two batches per block: waves 0-4 batch A, 5-9 batch B
#define CHW  128   // staging chunk width (columns)
#define GSTR 132   // GBUF row stride in floats (128 + 4 pad)

// =====================================================================
// Fast transform: tf(x) = sign(x) * (g(|x|+1e-5) - g(1e-5)),
//   g(t) = ln(1/t+1)^{-1.3} = exp2(-1.3*log2(log2(1/t+1)) + A),
//   A = -1.3*log2(ln2) = 0.68739628. 4 transcendentals vs reference's 8.
// =====================================================================
__device__ __forceinline__ float gfun(float t) {
  const float l2 = __log2f(__builtin_amdgcn_rcpf(t) + 1.0f);
  return __builtin_amdgcn_exp2f(fmaf(-1.3f, __log2f(l2), 0.68739628f));
}
__device__ __forceinline__ float simple_tf(float x, float Cg) {
  const float s = gfun(fabsf(x) + 1e-5f) - Cg;
  return (x >= 0.0f) ? s : -s;
}

// Fast fp64 reciprocal: v_rcp_f64 + 2 Newton -> full fp64 accuracy
// (validated R2-R5: absmax bit-identical to exact divide). Inputs > 0.
__device__ __forceinline__ double fdrcp(double d) {
  double r;
  asm("v_rcp_f64 %0, %1" : "=v"(r) : "v"(d));
  r = r * fma(-d, r, 2.0);
  r = r * fma(-d, r, 2.0);
  return r;
}

// Constant-lane fp64 broadcast via v_readlane (VALU, off the LDS pipe).
__device__ __forceinline__ double bcastd(double v, const int srclane) {
  const int lo = __builtin_amdgcn_readlane(__double2loint(v), srclane);
  const int hi = __builtin_amdgcn_readlane(__double2hiint(v), srclane);
  return __hiloint2double(hi, lo);
}

// In-place Gauss-Jordan of 25x25 SPD; columns live on lanes BASE..BASE+24.
template <int BASE, int J>
__device__ __forceinline__ void gjp(double (&a)[25], const int lane,
                                    const bool act) {
  const double djj = bcastd(a[J], BASE + J);
  const double pinv = fdrcp(djj);
  if (act) a[J] = ((lane == BASE + J) ? 1.0 : a[J]) * pinv;
#pragma unroll
  for (int r = 0; r < 25; ++r) {
    if (r != J) {
      const double f = bcastd(a[r], BASE + J);
      if (act) a[r] = ((lane == BASE + J) ? 0.0 : a[r]) - f * a[J];
    }
  }
}
template <int BASE, int J = 0>
__device__ __forceinline__ void gjall(double (&a)[25], const int lane,
                                      const bool act) {
  if constexpr (J < 25) {
    gjp<BASE, J>(a, lane, act);
    gjall<BASE, J + 1>(a, lane, act);
  }
}

// Factorize (per half): hv <- row `lane` of Hinv_w; this half's wave-0
// lanes 32-56 additionally get Winv = (sum_k Hinv_k)^-1 rows.
// W accumulation: write-first sequential waves (atomics/flag barriers
// were measured-negative).
__device__ __forceinline__ void factorize(const double* Msh, const double* dd,
                                          double* W, double (&hv)[25],
                                          const int tl, const int lane,
                                          const int w) {
  if (lane < 25) {
#pragma unroll
    for (int j = 0; j < 25; ++j)
      hv[j] = Msh[lane * 26 + j] + ((j == lane) ? dd[lane * 5 + w] : 0.0);
  }
  gjall<0>(hv, lane, true);
#pragma unroll
  for (int k = 0; k < 5; ++k) {
    if (w == k && lane < 25) {
      if (k == 0) {
#pragma unroll
        for (int j = 0; j < 25; ++j) W[lane * 26 + j] = hv[j];
      } else {
#pragma unroll
        for (int j = 0; j < 25; ++j) W[lane * 26 + j] += hv[j];
      }
    }
    __syncthreads();
  }
  if (w == 0) {
    if (lane >= 32 && lane < 57) {
#pragma unroll
      for (int r = 0; r < 25; ++r) hv[r] = W[(lane - 32) * 26 + r];
    }
    gjall<32>(hv, lane, lane >= 32 && lane < 57);
  }
  // next consumer phase begins with its own __syncthreads()
}

// KKT solve (per half). ZRS: rs==0; ZR: rx=rz=ry==0; ACC: accumulate.
// di = 1/dd precomputed -> the two per-solve divides become multiplies.
template <bool ZRS, bool ZR, bool ACC>
__device__ __forceinline__ void kkt_solve(
    const double* Msh, const double* dd, const double* di, double* tt,
    double* c1, double* c2, double* vv, double* gg, double* dyw,
    const double* rx, const double* rs, const double* rz, const double* ry,
    double (&hv)[25], double* dx, double* ds, double* dz, double* dy,
    const int tl, const int lane, const int w) {
  if (tl < NZV) {
    double t = ZR ? 0.0 : rz[tl];
    if (!ZRS) t -= rs[tl] * di[tl];
    tt[tl] = t;
  }
  __syncthreads();
  if (tl < NZV) {
    const int i = tl / 5, k = tl - i * 5;
    double acc = ZR ? 0.0 : -rx[tl];
#pragma unroll
    for (int j = 0; j < 25; ++j) acc += Msh[i * 26 + j] * tt[j * 5 + k];
    c1[tl] = acc;
  } else if (tl >= 128 && tl < 153) {
    const int i = tl - 128;
    double acc = ZR ? 0.0 : -ry[i];
#pragma unroll
    for (int k = 0; k < 5; ++k) acc += tt[i * 5 + k];
    c2[i] = acc;
  }
  __syncthreads();
  if (lane < 25) {
    double acc = 0.0;
#pragma unroll
    for (int j = 0; j < 25; ++j) acc += hv[j] * c1[j * 5 + w];
    vv[lane * 5 + w] = acc;
  }
  __syncthreads();
  if (w == 0) {  // gg then dy in the SAME wave: LDS program order suffices
    if (lane < 25) {
      double acc = -c2[lane];
#pragma unroll
      for (int k = 0; k < 5; ++k) acc += vv[lane * 5 + k];
      gg[lane] = acc;
    }
    if (lane >= 32 && lane < 57) {
      double acc = 0.0;
#pragma unroll
      for (int r = 0; r < 25; ++r) acc += hv[r] * gg[r];
      dyw[lane - 32] = acc;
      if (ACC) dy[lane - 32] += acc; else dy[lane - 32] = acc;
    }
  }
  __syncthreads();
  if (lane < 25) {
    double acc = 0.0;
#pragma unroll
    for (int j = 0; j < 25; ++j) acc += hv[j] * dyw[j];
    const int v = lane * 5 + w;
    const double u = vv[v] - acc;
    const double dzv = dd[v] * u;
    const double dxv = u - tt[v];
    const double dsv = ((ZRS ? 0.0 : -rs[v]) - dzv) * di[v];
    if (ACC) { dz[v] += dzv; dx[v] += dxv; ds[v] += dsv; }
    else     { dz[v]  = dzv; dx[v]  = dxv; ds[v]  = dsv; }
  }
  __syncthreads();
}

// Per-half block reduction over an LDS buffer (init-phase only).
__device__ __forceinline__ double bred(const double* buf, int n, int ismin,
                                       double* SCh, const int w,
                                       const int lane) {
  __syncthreads();
  if (w == 0) {
    double acc = ismin ? 1e300 : 0.0;
    for (int m = lane; m < n; m += 64) {
      const double v = buf[m];
      acc = ismin ? fmin(acc, v) : (acc + v);
    }
#pragma unroll
    for (int off = 32; off > 0; off >>= 1) {
      const double o = __shfl_xor(acc, off);
      acc = ismin ? fmin(acc, o) : (acc + o);
    }
    if (lane == 0) SCh[15] = acc;
  }
  __syncthreads();
  return SCh[15];
}

// ONE-barrier combine of per-thread values living on tl<125 (waves 0-1
// of the half). Callers pass identity for tl>=125. sb selects a 2-slot
// SC region; the 3 loop call-sites use disjoint slots so a slow wave
// reading site-N can never race site-(N+1)'s writes.
template <bool ISMIN>
__device__ __forceinline__ double bred2(double val, double* SCh, const int sb,
                                        const int w, const int lane) {
#pragma unroll
  for (int off = 32; off > 0; off >>= 1) {
    const double o = __shfl_xor(val, off);
    val = ISMIN ? fmin(val, o) : (val + o);
  }
  if (w < 2 && lane == 0) SCh[sb + w] = val;
  __syncthreads();
  return ISMIN ? fmin(SCh[sb], SCh[sb + 1]) : (SCh[sb] + SCh[sb + 1]);
}

// stage CHW columns of RAW transformed train rows into GBUF[25][GSTR].
// (Normalization folded into M-rescale and phase-4 weights.)
__device__ __forceinline__ void stage_chunk(const float* __restrict__ tb,
                                            const int ch, const bool us,
                                            const float Cg, float* GBUF,
                                            const int tl) {
  for (int idx = tl; idx < NSUP * CHW; idx += 320) {
    const int r = idx >> 7, cc = idx & (CHW - 1);
    float v = tb[r * DF + ch * CHW + cc];
    if (us) v = simple_tf(v, Cg);
    GBUF[r * GSTR + cc] = v;
  }
}

// =====================================================================
// qp_kernel: TWO batches per 640-thread block (waves 0-4 / 5-9), grid
// B/2 = 256 -> exactly 1 block/CU, 10 waves resident (PROVEN shape).
// NEW vs R5: waves_per_eu(2,3) lifts the compiler's 84-VGPR / 6-wave
// occupancy target (source of scratch spills + unbatchable ds_read
// chains in every matvec phase); CHW=128 staging halves Gram/phase-4
// barrier count; best_res in registers (-2 barriers/iter); bred2
// single-barrier reductions (-3 barriers + 3 LDS sweeps/iter).
// =====================================================================
__attribute__((amdgpu_waves_per_eu(2, 3)))
__global__ void __launch_bounds__(TPB) qp_kernel(
    const float* __restrict__ train, const int* __restrict__ usimple,
    float* __restrict__ xfg, const int B) {
  const int tid = threadIdx.x;
  const int half = tid >= 320 ? 1 : 0;
  const int tl = tid - 320 * half;
  const int lane = tid & 63;
  const int w = tl >> 6;
  const int bb = 2 * blockIdx.x + half;
  const bool live = bb < B;
  const bool us = (usimple[0] != 0);
  const float Cg = gfun(1e-5f);

  __shared__ double Msh_[2][650];
  __shared__ __align__(16) unsigned char GBW_[2][13200];  // GBUF / W union
  __shared__ double x_[2][125], s_[2][125], z_[2][125], rx_[2][125],
      rz_[2][125], dd_[2][125], di_[2][125], tt_[2][125], c1_[2][125],
      vv_[2][125], dxa_[2][125], dsa_[2][125], dza_[2][125], rsc_[2][125];
  __shared__ double yv_[2][25], ry_[2][25], c2_[2][25], gg_[2][25],
      dya_[2][25], dyw_[2][25];
  __shared__ double SC_[2][16];
  __shared__ float invn_[2][25];
  __shared__ float bxs_[2][125];

  double* Msh = Msh_[half];
  double* W = (double*)GBW_[half];       // factorize only
  float* GBUF = (float*)GBW_[half];      // Gram/phase-4 only (disjoint)
  double* x = x_[half];
  double* sv = s_[half];
  double* zv = z_[half];
  double* rx = rx_[half];
  double* rz = rz_[half];
  double* dd = dd_[half];
  double* di = di_[half];
  double* tt = tt_[half];
  double* c1 = c1_[half];
  double* vv = vv_[half];
  double* dxa = dxa_[half];
  double* dsa = dsa_[half];
  double* dza = dza_[half];
  double* rsc = rsc_[half];
  double* yv = yv_[half];
  double* ry = ry_[half];
  double* c2 = c2_[half];
  double* gg = gg_[half];
  double* dya = dya_[half];
  double* dyw = dyw_[half];
  double* SC = SC_[half];
  float* invn = invn_[half];
  float* bxs = bxs_[half];
  double* dinvn = c2;  // c2 is dead until the first kkt_solve
  double hv[25];

  const float* tb = train + (size_t)(live ? bb : 0) * NSUP * DF;

  // ---- phase 2: chunked RAW Gram G = F F^T (fp64 accumulate) ----
  int i1, j1, i2v = 0, j2v = 0;
  {
    int rem = tl, i = 0;
    while (rem >= NSUP - i) { rem -= NSUP - i; ++i; }
    i1 = i; j1 = i + rem;
  }
  if (tl < 5) {
    int rem = 320 + tl, i = 0;
    while (rem >= NSUP - i) { rem -= NSUP - i; ++i; }
    i2v = i; j2v = i + rem;
  }
  double acc1 = 0.0, acc2 = 0.0;
  for (int ch = 0; ch < DF / CHW; ++ch) {
    stage_chunk(tb, ch, us, Cg, GBUF, tl);
    __syncthreads();
    {
      const float4* ra = (const float4*)(GBUF + i1 * GSTR);
      const float4* rb = (const float4*)(GBUF + j1 * GSTR);
#pragma unroll
      for (int c = 0; c < CHW / 4; ++c) {
        float4 av = ra[c], bv = rb[c];
        acc1 += (double)av.x * bv.x + (double)av.y * bv.y +
                (double)av.z * bv.z + (double)av.w * bv.w;
      }
    }
    if (tl < 5) {
      const float4* ra = (const float4*)(GBUF + i2v * GSTR);
      const float4* rb = (const float4*)(GBUF + j2v * GSTR);
#pragma unroll
      for (int c = 0; c < CHW / 4; ++c) {
        float4 av = ra[c], bv = rb[c];
        acc2 += (double)av.x * bv.x + (double)av.y * bv.y +
                (double)av.z * bv.z + (double)av.w * bv.w;
      }
    }
    __syncthreads();
  }
  Msh[i1 * 26 + j1] = acc1;
  if (i1 != j1) Msh[j1 * 26 + i1] = acc1;
  if (tl < 5) {
    Msh[i2v * 26 + j2v] = acc2;
    if (i2v != j2v) Msh[j2v * 26 + i2v] = acc2;
  }
  __syncthreads();

  // ---- norms from Gram diagonal; rescale M = D G D + I ----
  if (tl < 25) {
    const double g = Msh[tl * 27];
    const double dn = 1.0 / fmax(sqrt(g), 1e-12);
    dinvn[tl] = dn;
    invn[tl] = (float)dn;
  }
  __syncthreads();
  for (int idx = tl; idx < 650; idx += 320) {
    const int i = idx / 26, j = idx - i * 26;
    if (j < 25) {
      double v = Msh[idx] * dinvn[i] * dinvn[j];
      if (i == j) v += 1.0;
      Msh[idx] = v;
    }
  }

  // ---- phase 3: QP init ----
  if (tl < NZV) {
    const int i = tl / 5, k = tl - i * 5;
    const double oh = (k == (i % 5)) ? 1.0 : 0.0;
    rx[tl] = -oh;
    rz[tl] = -0.1 * oh;
    dd[tl] = 1.0;
    di[tl] = 1.0;
  } else if (tl >= 128 && tl < 153) {
    ry[tl - 128] = 0.0;
  }
  __syncthreads();

  factorize(Msh, dd, W, hv, tl, lane, w);
  kkt_solve<true, false, false>(Msh, dd, di, tt, c1, c2, vv, gg, dyw, rx,
                                (const double*)nullptr, rz, ry, hv, x, sv, zv,
                                yv, tl, lane, w);
  {
    const double ms = bred(sv, NZV, 1, SC, w, lane);
    if (ms < 0.0 && tl < NZV) sv[tl] -= (ms - 1.0);
    const double mz = bred(zv, NZV, 1, SC, w, lane);
    if (mz < 0.0 && tl < NZV) zv[tl] -= (mz - 1.0);
  }
  if (tl < NZV) bxs[tl] = (float)x[tl];

  double best_res = 1e300;  // res is block-uniform -> track in registers

#pragma unroll 1
  for (int it = 0; it < 3; ++it) {
    __syncthreads();
    if (tl < NZV) {
      const int i = tl / 5, k = tl - i * 5;
      double acc = 0.0;
#pragma unroll
      for (int j = 0; j < 25; ++j) acc += Msh[i * 26 + j] * x[j * 5 + k];
      const double oh = (k == (i % 5)) ? 1.0 : 0.0;
      rx[tl] = yv[i] + zv[tl] + acc - oh;
      rz[tl] = x[tl] + sv[tl] - 0.1 * oh;
    } else if (tl >= 128 && tl < 153) {
      const int i = tl - 128;
      double acc = 0.0;
#pragma unroll
      for (int k = 0; k < 5; ++k) acc += x[i * 5 + k];
      ry[i] = acc;
    }
    __syncthreads();
    if (w == 0) {  // per-half consolidated 4-sum reduction (first wave)
      double s1 = 0, s2 = 0, s3 = 0, s4 = 0;
      for (int m = lane; m < 125; m += 64) {
        s1 += sv[m] * zv[m];
        s2 += rx[m] * rx[m];
        s3 += rz[m] * rz[m];
      }
      if (lane < 25) s4 = ry[lane] * ry[lane];
#pragma unroll
      for (int off = 32; off > 0; off >>= 1) {
        s1 += __shfl_xor(s1, off);
        s2 += __shfl_xor(s2, off);
        s3 += __shfl_xor(s3, off);
        s4 += __shfl_xor(s4, off);
      }
      if (lane == 0) { SC[2] = s1; SC[3] = s2; SC[4] = s3; SC[5] = s4; }
    }
    __syncthreads();
    const double szsum = SC[2];
    const double mu = fabs(szsum) / 125.0;
    const double res = sqrt(SC[4] + 1e-30) + sqrt(SC[5] + 1e-30) +
                       sqrt(SC[3] + 1e-30) + 125.0 * mu;
    if (res < best_res) {  // uniform branch; x stable since loop-top barrier
      best_res = res;
      if (tl < NZV) bxs[tl] = (float)x[tl];
    }
    if (it == 2) break;

    if (tl < NZV) {
      dd[tl] = zv[tl] * fdrcp(sv[tl]);
      di[tl] = sv[tl] * fdrcp(zv[tl]);
    }
    __syncthreads();
    factorize(Msh, dd, W, hv, tl, lane, w);
    kkt_solve<false, false, false>(Msh, dd, di, tt, c1, c2, vv, gg, dyw, rx,
                                   zv, rz, ry, hv, dxa, dsa, dza, dya, tl,
                                   lane, w);
    double am = 1e12;
    if (tl < NZV) {
      const double a1 = (dza[tl] < 0.0) ? (-zv[tl] / dza[tl]) : 1e12;
      const double a2 = (dsa[tl] < 0.0) ? (-sv[tl] / dsa[tl]) : 1e12;
      am = fmin(a1, a2);
    }
    const double aff = fmin(bred2<true>(am, SC, 8, w, lane), 1.0);
    double tp = 0.0;
    if (tl < NZV)
      tp = (sv[tl] + aff * dsa[tl]) * (zv[tl] + aff * dza[tl]);
    const double num = bred2<false>(tp, SC, 10, w, lane);
    const double sg = num / szsum;
    const double musig = mu * (sg * sg * sg);
    // rsc[tl] is written and read by the SAME thread inside kkt_solve's
    // first phase -> no barrier needed here.
    if (tl < NZV) rsc[tl] = (-musig + dsa[tl] * dza[tl]) * fdrcp(sv[tl]);
    kkt_solve<false, true, true>(Msh, dd, di, tt, c1, c2, vv, gg, dyw, rx,
                                 rsc, rz, ry, hv, dxa, dsa, dza, dya, tl,
                                 lane, w);
    am = 1e12;
    if (tl < NZV) {
      const double a1 = (dza[tl] < 0.0) ? (-zv[tl] / dza[tl]) : 1e12;
      const double a2 = (dsa[tl] < 0.0) ? (-sv[tl] / dsa[tl]) : 1e12;
      am = fmin(a1, a2);
    }
    const double al = fmin(0.999 * bred2<true>(am, SC, 12, w, lane), 1.0);
    if (tl < NZV) {
      x[tl] += al * dxa[tl];
      sv[tl] += al * dsa[tl];
      zv[tl] += al * dza[tl];
    } else if (tl >= 128 && tl < 153) {
      const int i = tl - 128;
      yv[i] += al * dya[i];
    }
  }
  __syncthreads();

  // ---- phase 4: xfg[w][d] = sum_s (bx[s,w]*invn[s]) * Fraw[s][d] ----
  float xs[25];
#pragma unroll
  for (int s_ = 0; s_ < 25; ++s_) xs[s_] = bxs[s_ * 5 + w] * invn[s_];
  for (int ch = 0; ch < DF / CHW; ++ch) {
    stage_chunk(tb, ch, us, Cg, GBUF, tl);
    __syncthreads();
    float accA = 0.0f, accB = 0.0f;
#pragma unroll
    for (int s_ = 0; s_ < 25; ++s_) {
      accA += xs[s_] * GBUF[s_ * GSTR + lane];
      accB += xs[s_] * GBUF[s_ * GSTR + 64 + lane];
    }
    if (live) {
      float* op = xfg + ((size_t)bb * NWAY + w) * DF + ch * CHW;
      op[lane] = accA;
      op[64 + lane] = accB;
    }
    __syncthreads();
  }
}

// =====================================================================
// Output kernel: TWO blocks per batch (even/odd queries), grid 2B.
// xfg rows held in REGISTERS (60 VGPR) instead of LDS: no staging
// pass, no __syncthreads at all; waves_per_eu cap keeps it spill-free.
// =====================================================================
__attribute__((amdgpu_waves_per_eu(2, 4)))
__global__ void __launch_bounds__(640) out_kernel(
    const float* __restrict__ test, const int* __restrict__ usimple,
    const float* __restrict__ xfg, float* __restrict__ out) {
  const int bid = blockIdx.x;
  const int b = bid >> 1;
  const int hh = bid & 1;   // even / odd queries
  const int tid = threadIdx.x;
  const int lane = tid & 63;
  const int u = tid >> 6;   // 0..9
  const bool us = (usimple[0] != 0);
  const float Cg = gfun(1e-5f);

  // lane covers float4 slots {lane, lane+64, lane+128(<160)} of each way
  const float4* xg4 = (const float4*)(xfg + (size_t)b * NWAY * DF);
  float4 xr[5][3];
#pragma unroll
  for (int wy = 0; wy < 5; ++wy) {
#pragma unroll
    for (int c = 0; c < 3; ++c) {
      if (c < 2 || lane < 32)
        xr[wy][c] = xg4[wy * (DF / 4) + lane + 64 * c];
    }
  }

  const float* qb = test + (size_t)b * NQ * DF;
#pragma unroll 2
  for (int jj = 0; jj < 4; ++jj) {
    const int q = 2 * (u + 10 * jj) + hh;
    if (q >= NQ) break;  // q monotone in jj
    const float4* qr4 = (const float4*)(qb + (size_t)q * DF);
    float nrm = 0.0f, a0 = 0.0f, a1 = 0.0f, a2 = 0.0f, a3 = 0.0f, a4 = 0.0f;
#pragma unroll
    for (int c = 0; c < 3; ++c) {
      if (c < 2 || lane < 32) {
        float4 vq = qr4[lane + 64 * c];
        if (us) {
          vq.x = simple_tf(vq.x, Cg);
          vq.y = simple_tf(vq.y, Cg);
          vq.z = simple_tf(vq.z, Cg);
          vq.w = simple_tf(vq.w, Cg);
        }
        nrm += vq.x * vq.x + vq.y * vq.y + vq.z * vq.z + vq.w * vq.w;
        a0 += vq.x * xr[0][c].x + vq.y * xr[0][c].y + vq.z * xr[0][c].z +
              vq.w * xr[0][c].w;
        a1 += vq.x * xr[1][c].x + vq.y * xr[1][c].y + vq.z * xr[1][c].z +
              vq.w * xr[1][c].w;
        a2 += vq.x * xr[2][c].x + vq.y * xr[2][c].y + vq.z * xr[2][c].z +
              vq.w * xr[2][c].w;
        a3 += vq.x * xr[3][c].x + vq.y * xr[3][c].y + vq.z * xr[3][c].z +
              vq.w * xr[3][c].w;
        a4 += vq.x * xr[4][c].x + vq.y * xr[4][c].y + vq.z * xr[4][c].z +
              vq.w * xr[4][c].w;
      }
    }
#pragma unroll
    for (int off = 32; off > 0; off >>= 1) {
      nrm += __shfl_xor(nrm, off);
      a0 += __shfl_xor(a0, off);
      a1 += __shfl_xor(a1, off);
      a2 += __shfl_xor(a2, off);
      a3 += __shfl_xor(a3, off);
      a4 += __shfl_xor(a4, off);
    }
    if (lane == 0) {
      const float sc = 1.0f / fmaxf(sqrtf(nrm), 1e-12f);
      float* op = out + ((size_t)b * NQ + q) * 5;
      op[0] = a0 * sc;
      op[1] = a1 * sc;
      op[2] = a2 * sc;
      op[3] = a3 * sc;
      op[4] = a4 * sc;
    }
  }
}

// =====================================================================
extern "C" void kernel_launch(void* const* d_in, const int* in_sizes, int n_in,
                              void* d_out, int out_size, void* d_ws,
                              size_t ws_size, hipStream_t stream) {
  const float* ftest = (const float*)d_in[0];
  const float* ftrain = (const float*)d_in[1];
  const int* usimple = (const int*)d_in[4];
  float* out = (float*)d_out;
  const int B = in_sizes[1] / (NSUP * DF);

  float* xfg = (float*)d_ws;  // B * 5 * 640 floats

  qp_kernel<<<dim3((B + 1) / 2), dim3(TPB), 0, stream>>>(ftrain, usimple,
                                                         xfg, B);
  out_kernel<<<dim3(2 * B), dim3(640), 0, stream>>>(ftest, usimple, xfg,
                                                    out);
}

// Round 7
// 453.428 us; speedup vs baseline: 1.6918x; 1.6918x over previous
//
#include <hip/hip_runtime.h>
#include <math.h>

#define NWAY 5
#define NSUP 25
#define NZV  125
#define DF   640
#define NQ   75
#define TPB  640   // two batches per block: waves 0-4 batch A, 5-9 batch B

// =====================================================================
// Fast transform: tf(x) = sign(x) * (g(|x|+1e-5) - g(1e-5)),
//   g(t) = ln(1/t+1)^{-1.3} = exp2(-1.3*log2(log2(1/t+1)) + A),
//   A = -1.3*log2(ln2) = 0.68739628. 4 transcendentals vs reference's 8.
// =====================================================================
__device__ __forceinline__ float gfun(float t) {
  const float l2 = __log2f(__builtin_amdgcn_rcpf(t) + 1.0f);
  return __builtin_amdgcn_exp2f(fmaf(-1.3f, __log2f(l2), 0.68739628f));
}
__device__ __forceinline__ float simple_tf(float x, float Cg) {
  const float s = gfun(fabsf(x) + 1e-5f) - Cg;
  return (x >= 0.0f) ? s : -s;
}

// Fast fp64 reciprocal: v_rcp_f64 + 2 Newton -> full fp64 accuracy
// (validated R2-R6: absmax bit-identical to exact divide). Inputs > 0.
__device__ __forceinline__ double fdrcp(double d) {
  double r;
  asm("v_rcp_f64 %0, %1" : "=v"(r) : "v"(d));
  r = r * fma(-d, r, 2.0);
  r = r * fma(-d, r, 2.0);
  return r;
}

// Constant-lane fp64 broadcast via v_readlane (VALU, off the LDS pipe).
__device__ __forceinline__ double bcastd(double v, const int srclane) {
  const int lo = __builtin_amdgcn_readlane(__double2loint(v), srclane);
  const int hi = __builtin_amdgcn_readlane(__double2hiint(v), srclane);
  return __hiloint2double(hi, lo);
}

// In-place Gauss-Jordan of 25x25 SPD; columns live on lanes BASE..BASE+24.
template <int BASE, int J>
__device__ __forceinline__ void gjp(double (&a)[25], const int lane,
                                    const bool act) {
  const double djj = bcastd(a[J], BASE + J);
  const double pinv = fdrcp(djj);
  if (act) a[J] = ((lane == BASE + J) ? 1.0 : a[J]) * pinv;
#pragma unroll
  for (int r = 0; r < 25; ++r) {
    if (r != J) {
      const double f = bcastd(a[r], BASE + J);
      if (act) a[r] = ((lane == BASE + J) ? 0.0 : a[r]) - f * a[J];
    }
  }
}
template <int BASE, int J = 0>
__device__ __forceinline__ void gjall(double (&a)[25], const int lane,
                                      const bool act) {
  if constexpr (J < 25) {
    gjp<BASE, J>(a, lane, act);
    gjall<BASE, J + 1>(a, lane, act);
  }
}

// Factorize (per half): hv <- row `lane` of Hinv_w; this half's wave-0
// lanes 32-56 additionally get Winv = (sum_k Hinv_k)^-1 rows.
// INIT (dd==1): all H_k identical -> Winv = (M+I)/5 analytically; no
// dump, no extra GJ, ZERO barriers (validated R4).
// Loop: private Hs dump + 1 barrier + wave-0 gather-sum (5 -> 1
// barrier; validated R4).
template <bool INIT>
__device__ __forceinline__ void factorize(const double* Msh, const double* dd,
                                          double* Hs, double (&hv)[25],
                                          const int tl, const int lane,
                                          const int w) {
  if (lane < 25) {
#pragma unroll
    for (int j = 0; j < 25; ++j)
      hv[j] = Msh[lane * 26 + j] +
              ((j == lane) ? (INIT ? 1.0 : dd[lane * 5 + w]) : 0.0);
  }
  if (INIT) {
    // Winv rows BEFORE the GJ (disjoint lanes; act mask preserves them).
    if (w == 0 && lane >= 32 && lane < 57) {
      const int i = lane - 32;
#pragma unroll
      for (int r = 0; r < 25; ++r)
        hv[r] = 0.2 * (Msh[i * 26 + r] + ((i == r) ? 1.0 : 0.0));
    }
    gjall<0>(hv, lane, lane < 25);
  } else {
    gjall<0>(hv, lane, lane < 25);
    if (lane < 25) {
#pragma unroll
      for (int j = 0; j < 25; ++j) Hs[(w * 25 + lane) * 25 + j] = hv[j];
    }
    __syncthreads();
    if (w == 0) {
      if (lane >= 32 && lane < 57) {
        const int i = lane - 32;
#pragma unroll
        for (int r = 0; r < 25; ++r) {
          double a = 0.0;
#pragma unroll
          for (int k = 0; k < 5; ++k) a += Hs[(k * 25 + i) * 25 + r];
          hv[r] = a;
        }
      }
      gjall<32>(hv, lane, lane >= 32 && lane < 57);
    }
  }
  // next consumer phase begins with its own __syncthreads()
}

// KKT solve (per half). ZRS: rs==0; ZR: rx=rz=ry==0; ACC: accumulate.
// di = 1/dd precomputed -> the two per-solve divides become multiplies.
template <bool ZRS, bool ZR, bool ACC>
__device__ __forceinline__ void kkt_solve(
    const double* Msh, const double* dd, const double* di, double* tt,
    double* c1, double* c2, double* vv, double* gg, double* dyw,
    const double* rx, const double* rs, const double* rz, const double* ry,
    double (&hv)[25], double* dx, double* ds, double* dz, double* dy,
    const int tl, const int lane, const int w) {
  if (tl < NZV) {
    double t = ZR ? 0.0 : rz[tl];
    if (!ZRS) t -= rs[tl] * di[tl];
    tt[tl] = t;
  }
  __syncthreads();
  if (tl < NZV) {
    const int i = tl / 5, k = tl - i * 5;
    double acc = ZR ? 0.0 : -rx[tl];
#pragma unroll
    for (int j = 0; j < 25; ++j) acc += Msh[i * 26 + j] * tt[j * 5 + k];
    c1[tl] = acc;
  } else if (tl >= 128 && tl < 153) {
    const int i = tl - 128;
    double acc = ZR ? 0.0 : -ry[i];
#pragma unroll
    for (int k = 0; k < 5; ++k) acc += tt[i * 5 + k];
    c2[i] = acc;
  }
  __syncthreads();
  if (lane < 25) {
    double acc = 0.0;
#pragma unroll
    for (int j = 0; j < 25; ++j) acc += hv[j] * c1[j * 5 + w];
    vv[lane * 5 + w] = acc;
  }
  __syncthreads();
  if (w == 0) {  // gg then dy in the SAME wave: LDS program order suffices
    if (lane < 25) {
      double acc = -c2[lane];
#pragma unroll
      for (int k = 0; k < 5; ++k) acc += vv[lane * 5 + k];
      gg[lane] = acc;
    }
    if (lane >= 32 && lane < 57) {
      double acc = 0.0;
#pragma unroll
      for (int r = 0; r < 25; ++r) acc += hv[r] * gg[r];
      dyw[lane - 32] = acc;
      if (ACC) dy[lane - 32] += acc; else dy[lane - 32] = acc;
    }
  }
  __syncthreads();
  if (lane < 25) {
    double acc = 0.0;
#pragma unroll
    for (int j = 0; j < 25; ++j) acc += hv[j] * dyw[j];
    const int v = lane * 5 + w;
    const double u = vv[v] - acc;
    const double dzv = dd[v] * u;
    const double dxv = u - tt[v];
    const double dsv = ((ZRS ? 0.0 : -rs[v]) - dzv) * di[v];
    if (ACC) { dz[v] += dzv; dx[v] += dxv; ds[v] += dsv; }
    else     { dz[v]  = dzv; dx[v]  = dxv; ds[v]  = dsv; }
  }
  __syncthreads();
}

// Per-half block reduction over an LDS buffer (init-phase only).
__device__ __forceinline__ double bred(const double* buf, int n, int ismin,
                                       double* SCh, const int w,
                                       const int lane) {
  __syncthreads();
  if (w == 0) {
    double acc = ismin ? 1e300 : 0.0;
    for (int m = lane; m < n; m += 64) {
      const double v = buf[m];
      acc = ismin ? fmin(acc, v) : (acc + v);
    }
#pragma unroll
    for (int off = 32; off > 0; off >>= 1) {
      const double o = __shfl_xor(acc, off);
      acc = ismin ? fmin(acc, o) : (acc + o);
    }
    if (lane == 0) SCh[15] = acc;
  }
  __syncthreads();
  return SCh[15];
}

// ONE-barrier combine of per-thread register values (waves 2-4 pass
// identity). sb selects a disjoint 2-slot SC region per call-site;
// barriers between successive uses of the same slot are guaranteed by
// the surrounding phase structure.
template <bool ISMIN>
__device__ __forceinline__ double bred2(double val, double* SCh, const int sb,
                                        const int w, const int lane) {
#pragma unroll
  for (int off = 32; off > 0; off >>= 1) {
    const double o = __shfl_xor(val, off);
    val = ISMIN ? fmin(val, o) : (val + o);
  }
  if (w < 2 && lane == 0) SCh[sb + w] = val;
  __syncthreads();
  return ISMIN ? fmin(SCh[sb], SCh[sb + 1]) : (SCh[sb] + SCh[sb + 1]);
}

// stage 64 columns of RAW transformed train rows into GBUF[25][68].
// CHW=64 is LOAD-BEARING: 128-wide staging (R3/R4/R6) blows the VGPR
// budget via the unrolled float4 Gram loop -> hv spills to scratch ->
// ~600 MB HBM traffic and 2.2x slowdown.
__device__ __forceinline__ void stage_chunk(const float* __restrict__ tb,
                                            const int ch, const bool us,
                                            const float Cg, float* GBUF,
                                            const int tl) {
  for (int idx = tl; idx < 1600; idx += 320) {
    const int r = idx >> 6, cc = idx & 63;
    float v = tb[r * DF + (ch << 6) + cc];
    if (us) v = simple_tf(v, Cg);
    GBUF[r * 68 + cc] = v;
  }
}

// =====================================================================
// qp_kernel: TWO batches per 640-thread block (waves 0-4 / 5-9), grid
// B/2 = 256 -> exactly 1 block/CU, 10 waves resident (PROVEN shape).
// Deltas vs R5 (441.9us best): analytic init-Winv + Hs-dump factorize
// (-16 barriers), bred2 register reductions (-3 barriers + 3 LDS
// sweeps/iter), best_res in registers (-2 barriers/iter), rsc barrier
// dropped (same-thread). Staging/Gram codegen untouched (CHW=64).
// =====================================================================
__global__ void __launch_bounds__(TPB) qp_kernel(
    const float* __restrict__ train, const int* __restrict__ usimple,
    float* __restrict__ xfg, const int B) {
  const int tid = threadIdx.x;
  const int half = tid >= 320 ? 1 : 0;
  const int tl = tid - 320 * half;
  const int lane = tid & 63;
  const int w = tl >> 6;
  const int bb = 2 * blockIdx.x + half;
  const bool live = bb < B;
  const bool us = (usimple[0] != 0);
  const float Cg = gfun(1e-5f);

  __shared__ double Msh_[2][650];
  // Hs (3125 d, loop factorize) / GBUF (1700 f, Gram+phase4) union
  __shared__ __align__(16) unsigned char GBW_[2][25024];
  __shared__ double x_[2][125], s_[2][125], z_[2][125], rx_[2][125],
      rz_[2][125], dd_[2][125], di_[2][125], tt_[2][125], c1_[2][125],
      vv_[2][125], dxa_[2][125], dsa_[2][125], dza_[2][125], rsc_[2][125];
  __shared__ double yv_[2][25], ry_[2][25], c2_[2][25], gg_[2][25],
      dya_[2][25], dyw_[2][25];
  __shared__ double SC_[2][16];
  __shared__ float invn_[2][25];
  __shared__ float bxs_[2][125];

  double* Msh = Msh_[half];
  double* Hs = (double*)GBW_[half];      // loop factorize only
  float* GBUF = (float*)GBW_[half];      // Gram/phase-4 only (disjoint)
  double* x = x_[half];
  double* sv = s_[half];
  double* zv = z_[half];
  double* rx = rx_[half];
  double* rz = rz_[half];
  double* dd = dd_[half];
  double* di = di_[half];
  double* tt = tt_[half];
  double* c1 = c1_[half];
  double* vv = vv_[half];
  double* dxa = dxa_[half];
  double* dsa = dsa_[half];
  double* dza = dza_[half];
  double* rsc = rsc_[half];
  double* yv = yv_[half];
  double* ry = ry_[half];
  double* c2 = c2_[half];
  double* gg = gg_[half];
  double* dya = dya_[half];
  double* dyw = dyw_[half];
  double* SC = SC_[half];
  float* invn = invn_[half];
  float* bxs = bxs_[half];
  double* dinvn = c2;  // c2 is dead until the first kkt_solve
  double hv[25];

  const float* tb = train + (size_t)(live ? bb : 0) * NSUP * DF;

  // ---- phase 2: chunked RAW Gram G = F F^T (fp64 accumulate) ----
  int i1, j1, i2v = 0, j2v = 0;
  {
    int rem = tl, i = 0;
    while (rem >= NSUP - i) { rem -= NSUP - i; ++i; }
    i1 = i; j1 = i + rem;
  }
  if (tl < 5) {
    int rem = 320 + tl, i = 0;
    while (rem >= NSUP - i) { rem -= NSUP - i; ++i; }
    i2v = i; j2v = i + rem;
  }
  double acc1 = 0.0, acc2 = 0.0;
  for (int ch = 0; ch < 10; ++ch) {
    stage_chunk(tb, ch, us, Cg, GBUF, tl);
    __syncthreads();
    {
      const float4* ra = (const float4*)(GBUF + i1 * 68);
      const float4* rb = (const float4*)(GBUF + j1 * 68);
#pragma unroll
      for (int c = 0; c < 16; ++c) {
        float4 av = ra[c], bv = rb[c];
        acc1 += (double)av.x * bv.x + (double)av.y * bv.y +
                (double)av.z * bv.z + (double)av.w * bv.w;
      }
    }
    if (tl < 5) {
      const float4* ra = (const float4*)(GBUF + i2v * 68);
      const float4* rb = (const float4*)(GBUF + j2v * 68);
#pragma unroll
      for (int c = 0; c < 16; ++c) {
        float4 av = ra[c], bv = rb[c];
        acc2 += (double)av.x * bv.x + (double)av.y * bv.y +
                (double)av.z * bv.z + (double)av.w * bv.w;
      }
    }
    __syncthreads();
  }
  Msh[i1 * 26 + j1] = acc1;
  if (i1 != j1) Msh[j1 * 26 + i1] = acc1;
  if (tl < 5) {
    Msh[i2v * 26 + j2v] = acc2;
    if (i2v != j2v) Msh[j2v * 26 + i2v] = acc2;
  }
  __syncthreads();

  // ---- norms from Gram diagonal; rescale M = D G D + I ----
  if (tl < 25) {
    const double g = Msh[tl * 27];
    const double dn = 1.0 / fmax(sqrt(g), 1e-12);
    dinvn[tl] = dn;
    invn[tl] = (float)dn;
  }
  __syncthreads();
  for (int idx = tl; idx < 650; idx += 320) {
    const int i = idx / 26, j = idx - i * 26;
    if (j < 25) {
      double v = Msh[idx] * dinvn[i] * dinvn[j];
      if (i == j) v += 1.0;
      Msh[idx] = v;
    }
  }

  // ---- phase 3: QP init ----
  if (tl < NZV) {
    const int i = tl / 5, k = tl - i * 5;
    const double oh = (k == (i % 5)) ? 1.0 : 0.0;
    rx[tl] = -oh;
    rz[tl] = -0.1 * oh;
    dd[tl] = 1.0;
    di[tl] = 1.0;
  } else if (tl >= 128 && tl < 153) {
    ry[tl - 128] = 0.0;
  }
  __syncthreads();

  factorize<true>(Msh, dd, Hs, hv, tl, lane, w);
  kkt_solve<true, false, false>(Msh, dd, di, tt, c1, c2, vv, gg, dyw, rx,
                                (const double*)nullptr, rz, ry, hv, x, sv, zv,
                                yv, tl, lane, w);
  {
    const double ms = bred(sv, NZV, 1, SC, w, lane);
    if (ms < 0.0 && tl < NZV) sv[tl] -= (ms - 1.0);
    const double mz = bred(zv, NZV, 1, SC, w, lane);
    if (mz < 0.0 && tl < NZV) zv[tl] -= (mz - 1.0);
  }
  if (tl < NZV) bxs[tl] = (float)x[tl];

  double best_res = 1e300;  // res is block-uniform -> track in registers

#pragma unroll 1
  for (int it = 0; it < 3; ++it) {
    __syncthreads();
    if (tl < NZV) {
      const int i = tl / 5, k = tl - i * 5;
      double acc = 0.0;
#pragma unroll
      for (int j = 0; j < 25; ++j) acc += Msh[i * 26 + j] * x[j * 5 + k];
      const double oh = (k == (i % 5)) ? 1.0 : 0.0;
      rx[tl] = yv[i] + zv[tl] + acc - oh;
      rz[tl] = x[tl] + sv[tl] - 0.1 * oh;
    } else if (tl >= 128 && tl < 153) {
      const int i = tl - 128;
      double acc = 0.0;
#pragma unroll
      for (int k = 0; k < 5; ++k) acc += x[i * 5 + k];
      ry[i] = acc;
    }
    __syncthreads();
    if (w == 0) {  // per-half consolidated 4-sum reduction (first wave)
      double s1 = 0, s2 = 0, s3 = 0, s4 = 0;
      for (int m = lane; m < 125; m += 64) {
        s1 += sv[m] * zv[m];
        s2 += rx[m] * rx[m];
        s3 += rz[m] * rz[m];
      }
      if (lane < 25) s4 = ry[lane] * ry[lane];
#pragma unroll
      for (int off = 32; off > 0; off >>= 1) {
        s1 += __shfl_xor(s1, off);
        s2 += __shfl_xor(s2, off);
        s3 += __shfl_xor(s3, off);
        s4 += __shfl_xor(s4, off);
      }
      if (lane == 0) { SC[2] = s1; SC[3] = s2; SC[4] = s3; SC[5] = s4; }
    }
    __syncthreads();
    const double szsum = SC[2];
    const double mu = fabs(szsum) / 125.0;
    const double res = sqrt(SC[4] + 1e-30) + sqrt(SC[5] + 1e-30) +
                       sqrt(SC[3] + 1e-30) + 125.0 * mu;
    if (res < best_res) {  // uniform branch; x stable since loop-top barrier
      best_res = res;
      if (tl < NZV) bxs[tl] = (float)x[tl];
    }
    if (it == 2) break;

    if (tl < NZV) {
      dd[tl] = zv[tl] * fdrcp(sv[tl]);
      di[tl] = sv[tl] * fdrcp(zv[tl]);
    }
    __syncthreads();  // dd read cross-thread in factorize/kkt
    factorize<false>(Msh, dd, Hs, hv, tl, lane, w);
    kkt_solve<false, false, false>(Msh, dd, di, tt, c1, c2, vv, gg, dyw, rx,
                                   zv, rz, ry, hv, dxa, dsa, dza, dya, tl,
                                   lane, w);
    double am = 1e12;
    if (tl < NZV) {
      const double a1 = (dza[tl] < 0.0) ? (-zv[tl] / dza[tl]) : 1e12;
      const double a2 = (dsa[tl] < 0.0) ? (-sv[tl] / dsa[tl]) : 1e12;
      am = fmin(a1, a2);
    }
    const double aff = fmin(bred2<true>(am, SC, 8, w, lane), 1.0);
    double tp = 0.0;
    if (tl < NZV)
      tp = (sv[tl] + aff * dsa[tl]) * (zv[tl] + aff * dza[tl]);
    const double num = bred2<false>(tp, SC, 10, w, lane);
    const double sg = num / szsum;
    const double musig = mu * (sg * sg * sg);
    // rsc[tl] produced and consumed by the SAME thread in kkt phase 1;
    // the only cross-thread rsc read (phase 5) is behind >=4 barriers.
    if (tl < NZV) rsc[tl] = (-musig + dsa[tl] * dza[tl]) * fdrcp(sv[tl]);
    kkt_solve<false, true, true>(Msh, dd, di, tt, c1, c2, vv, gg, dyw, rx,
                                 rsc, rz, ry, hv, dxa, dsa, dza, dya, tl,
                                 lane, w);
    am = 1e12;
    if (tl < NZV) {
      const double a1 = (dza[tl] < 0.0) ? (-zv[tl] / dza[tl]) : 1e12;
      const double a2 = (dsa[tl] < 0.0) ? (-sv[tl] / dsa[tl]) : 1e12;
      am = fmin(a1, a2);
    }
    const double al = fmin(0.999 * bred2<true>(am, SC, 12, w, lane), 1.0);
    if (tl < NZV) {
      x[tl] += al * dxa[tl];
      sv[tl] += al * dsa[tl];
      zv[tl] += al * dza[tl];
    } else if (tl >= 128 && tl < 153) {
      const int i = tl - 128;
      yv[i] += al * dya[i];
    }
  }
  __syncthreads();

  // ---- phase 4: xfg[w][d] = sum_s (bx[s,w]*invn[s]) * Fraw[s][d] ----
  float xs[25];
#pragma unroll
  for (int s_ = 0; s_ < 25; ++s_) xs[s_] = bxs[s_ * 5 + w] * invn[s_];
  for (int ch = 0; ch < 10; ++ch) {
    stage_chunk(tb, ch, us, Cg, GBUF, tl);
    __syncthreads();
    float acc = 0.0f;
#pragma unroll
    for (int s_ = 0; s_ < 25; ++s_) acc += xs[s_] * GBUF[s_ * 68 + lane];
    if (live)
      xfg[((size_t)bb * NWAY + w) * DF + (ch << 6) + lane] = acc;
    __syncthreads();
  }
}

// =====================================================================
// Output kernel: TWO blocks per batch (even/odd queries), grid 2B,
// small LDS (12.8 KB) so blocks co-reside. float4 loads (3/query).
// =====================================================================
__global__ void __launch_bounds__(640) out_kernel(
    const float* __restrict__ test, const int* __restrict__ usimple,
    const float* __restrict__ xfg, float* __restrict__ out) {
  const int bid = blockIdx.x;
  const int b = bid >> 1;
  const int hh = bid & 1;   // even / odd queries
  const int tid = threadIdx.x;
  const int lane = tid & 63;
  const int u = tid >> 6;   // 0..9
  const bool us = (usimple[0] != 0);
  const float Cg = gfun(1e-5f);

  __shared__ float xfs[NWAY * DF];
  for (int i = tid; i < NWAY * DF; i += 640)
    xfs[i] = xfg[(size_t)b * NWAY * DF + i];
  __syncthreads();
  const float4* xf4 = (const float4*)xfs;

  const float* qb = test + (size_t)b * NQ * DF;
#pragma unroll 2
  for (int jj = 0; jj < 4; ++jj) {
    const int q = 2 * (u + 10 * jj) + hh;
    if (q >= NQ) break;  // q monotone in jj
    const float4* qr4 = (const float4*)(qb + (size_t)q * DF);
    float nrm = 0.0f, a0 = 0.0f, a1 = 0.0f, a2 = 0.0f, a3 = 0.0f, a4 = 0.0f;
#pragma unroll
    for (int c = 0; c < 3; ++c) {
      if (c < 2 || lane < 32) {
        const int f4i = lane + 64 * c;
        float4 vq = qr4[f4i];
        if (us) {
          vq.x = simple_tf(vq.x, Cg);
          vq.y = simple_tf(vq.y, Cg);
          vq.z = simple_tf(vq.z, Cg);
          vq.w = simple_tf(vq.w, Cg);
        }
        nrm += vq.x * vq.x + vq.y * vq.y + vq.z * vq.z + vq.w * vq.w;
        float4 t;
        t = xf4[0 * (DF / 4) + f4i];
        a0 += vq.x * t.x + vq.y * t.y + vq.z * t.z + vq.w * t.w;
        t = xf4[1 * (DF / 4) + f4i];
        a1 += vq.x * t.x + vq.y * t.y + vq.z * t.z + vq.w * t.w;
        t = xf4[2 * (DF / 4) + f4i];
        a2 += vq.x * t.x + vq.y * t.y + vq.z * t.z + vq.w * t.w;
        t = xf4[3 * (DF / 4) + f4i];
        a3 += vq.x * t.x + vq.y * t.y + vq.z * t.z + vq.w * t.w;
        t = xf4[4 * (DF / 4) + f4i];
        a4 += vq.x * t.x + vq.y * t.y + vq.z * t.z + vq.w * t.w;
      }
    }
#pragma unroll
    for (int off = 32; off > 0; off >>= 1) {
      nrm += __shfl_xor(nrm, off);
      a0 += __shfl_xor(a0, off);
      a1 += __shfl_xor(a1, off);
      a2 += __shfl_xor(a2, off);
      a3 += __shfl_xor(a3, off);
      a4 += __shfl_xor(a4, off);
    }
    if (lane == 0) {
      const float sc = 1.0f / fmaxf(sqrtf(nrm), 1e-12f);
      float* op = out + ((size_t)b * NQ + q) * 5;
      op[0] = a0 * sc;
      op[1] = a1 * sc;
      op[2] = a2 * sc;
      op[3] = a3 * sc;
      op[4] = a4 * sc;
    }
  }
}

// =====================================================================
extern "C" void kernel_launch(void* const* d_in, const int* in_sizes, int n_in,
                              void* d_out, int out_size, void* d_ws,
                              size_t ws_size, hipStream_t stream) {
  const float* ftest = (const float*)d_in[0];
  const float* ftrain = (const float*)d_in[1];
  const int* usimple = (const int*)d_in[4];
  float* out = (float*)d_out;
  const int B = in_sizes[1] / (NSUP * DF);

  float* xfg = (float*)d_ws;  // B * 5 * 640 floats

  qp_kernel<<<dim3((B + 1) / 2), dim3(TPB), 0, stream>>>(ftrain, usimple,
                                                         xfg, B);
  out_kernel<<<dim3(2 * B), dim3(640), 0, stream>>>(ftest, usimple, xfg,
                                                    out);
}